// Round 8
// baseline (199.627 us; speedup 1.0000x reference)
//
#include <hip/hip_runtime.h>
#include <hip/hip_cooperative_groups.h>
#include <hip/hip_bf16.h>

namespace cg = cooperative_groups;

// MessagePassing: out[dst[e], :] += x[src[e], :] * w[e]
// x: [N, 64] f32, edge_index: [2, E] int32 (row0=src, row1=dst), w: [E,1] f32
// out: [N, 64] f32
//
// Round-17: 4 consecutive nulls on K1/K2 internals (MLP, locality, tail,
// write granularity) while dur_us stays pinned at 124-127 across wildly
// different structures -> suspect the invariant is the 3-dispatch launch
// structure (memset + K1 + full drain + K2), not kernel internals.
// This round: ONE cooperative kernel. Stage0 zeros scratch (kills memset
// dispatch); phase A = work-stealing partition chunks + x->bf16 tiles
// (kills stragglers); grid.sync(); phase B = per-bin sort + gather
// (r10-proven geometry, 128-node bins, 512 threads).

constexpr int D_FEAT        = 64;
constexpr int BIN_SHIFT     = 7;                  // 128 nodes / bin
constexpr int NODES_PER_BIN = 1 << BIN_SHIFT;
constexpr int NBINS_MAX     = 1024;               // supports n_nodes <= 131072
constexpr int BIN_CAP       = 2048;               // mean 1536 at E/N=12 -> +13 sigma
constexpr int EPB           = 2048;               // edges per chunk (512 thr x int4)
constexpr int OVF_CAP       = 32768;
constexpr int CONV_TILE     = 2048;               // float4s per conversion tile

__device__ __forceinline__ int wave_incl_scan(int v, int lane) {
    #pragma unroll
    for (int d = 1; d < 64; d <<= 1) {
        int t = __shfl_up(v, d);
        if (lane >= d) v += t;
    }
    return v;
}

__device__ __forceinline__ unsigned short f32_to_bf16_rn(float f) {
    unsigned int u = __float_as_uint(f);
    u += 0x7FFFu + ((u >> 16) & 1u);
    return (unsigned short)(u >> 16);
}

// LDS: phase A and phase B never overlap (grid.sync between) -> union.
union SMemU {
    struct {                                       // 36 KB
        int cnt[NBINS_MAX];
        int start[NBINS_MAX];
        int cur[NBINS_MAX];
        int gbase[NBINS_MAX];
        unsigned short binof[EPB];
        int2 sorted[EPB];
    } a;
    struct {                                       // ~33.5 KB
        int2 sraw[BIN_CAP];
        int2 sedge[BIN_CAP];
        int ncnt[NODES_PER_BIN];
        int nstart[NODES_PER_BIN + 1];
        int ncur[NODES_PER_BIN];
    } b;
};

#define ACC8(XV, WW) do {                                          \
    a0 = fmaf(__uint_as_float((XV).x << 16),         (WW), a0);    \
    a1 = fmaf(__uint_as_float((XV).x & 0xFFFF0000u), (WW), a1);    \
    a2 = fmaf(__uint_as_float((XV).y << 16),         (WW), a2);    \
    a3 = fmaf(__uint_as_float((XV).y & 0xFFFF0000u), (WW), a3);    \
    a4 = fmaf(__uint_as_float((XV).z << 16),         (WW), a4);    \
    a5 = fmaf(__uint_as_float((XV).z & 0xFFFF0000u), (WW), a5);    \
    a6 = fmaf(__uint_as_float((XV).w << 16),         (WW), a6);    \
    a7 = fmaf(__uint_as_float((XV).w & 0xFFFF0000u), (WW), a7);    \
} while (0)

// misc layout (ints): [0]=chunk cursor, [16]=conv cursor, [32]=ovf counter
__global__ __launch_bounds__(512) void mp_fused(
    const int* __restrict__ src, const int* __restrict__ dst,
    const float* __restrict__ w, const float* __restrict__ x,
    ushort* __restrict__ xb, int n4,
    int* __restrict__ gcnt, int2* __restrict__ payload,
    int* __restrict__ misc, int4* __restrict__ ovf,
    float* __restrict__ out,
    int n_edges, int n_nodes, int nbins, int nchunks, int nconv)
{
    __shared__ SMemU sm;
    __shared__ int wsum[8];
    __shared__ int sc;

    const int t    = threadIdx.x;
    const int wid  = t >> 6;
    const int lane = t & 63;
    const int bid  = blockIdx.x;
    const int gsz  = gridDim.x;

    // ---- stage 0: zero global scratch (replaces host memset dispatch) ----
    for (int i = bid * 512 + t; i < NBINS_MAX + 64; i += gsz * 512) {
        if (i < NBINS_MAX) gcnt[i] = 0;
        else misc[i - NBINS_MAX] = 0;
    }
    cg::this_grid().sync();

    // ---- phase A1: partition edge chunks (work-stealing) ----
    for (;;) {
        if (t == 0) sc = atomicAdd(&misc[0], 1);
        __syncthreads();
        const int c = sc;
        __syncthreads();
        if (c >= nchunks) break;

        sm.a.cnt[t]       = 0;
        sm.a.cnt[t + 512] = 0;

        const int base = c * EPB;
        const int nblk = min(EPB, n_edges - base);
        const int i4   = (base >> 2) + t;
        const bool have = (i4 * 4 < n_edges);
        int4 d4 = make_int4(0, 0, 0, 0);
        if (have) d4 = reinterpret_cast<const int4*>(dst)[i4];
        __syncthreads();

        if (have) {
            atomicAdd(&sm.a.cnt[d4.x >> BIN_SHIFT], 1);
            atomicAdd(&sm.a.cnt[d4.y >> BIN_SHIFT], 1);
            atomicAdd(&sm.a.cnt[d4.z >> BIN_SHIFT], 1);
            atomicAdd(&sm.a.cnt[d4.w >> BIN_SHIFT], 1);
        }
        __syncthreads();

        // scan 1024 counters with 8 waves (128 keys each)
        {
            const int b0 = wid * 128;
            const int c0 = sm.a.cnt[b0 + lane];
            const int c1 = sm.a.cnt[b0 + 64 + lane];
            const int s0_ = wave_incl_scan(c0, lane);
            const int t0  = __shfl(s0_, 63);
            const int s1_ = wave_incl_scan(c1, lane) + t0;
            if (lane == 63) wsum[wid] = s1_;
            __syncthreads();
            int cpre = 0;
            #pragma unroll
            for (int k = 0; k < 8; ++k) cpre += (k < wid) ? wsum[k] : 0;
            const int e0 = cpre + s0_ - c0;
            const int e1 = cpre + s1_ - c1;
            sm.a.start[b0 + lane]      = e0;  sm.a.cur[b0 + lane]      = e0;
            sm.a.start[b0 + 64 + lane] = e1;  sm.a.cur[b0 + 64 + lane] = e1;
        }
        // reserve global per-bin bases
        for (int k = t; k < nbins; k += 512) {
            const int cc = sm.a.cnt[k];
            if (cc > 0) sm.a.gbase[k] = atomicAdd(&gcnt[k], cc);
        }
        __syncthreads();

        if (have) {
            const int4   s4 = reinterpret_cast<const int4*>(src)[i4];
            const float4 w4 = reinterpret_cast<const float4*>(w)[i4];
            const int   dd[4] = {d4.x, d4.y, d4.z, d4.w};
            const int   ss[4] = {s4.x, s4.y, s4.z, s4.w};
            const float ww[4] = {w4.x, w4.y, w4.z, w4.w};
            #pragma unroll
            for (int j = 0; j < 4; ++j) {
                const int b   = dd[j] >> BIN_SHIFT;
                const int low = dd[j] & (NODES_PER_BIN - 1);
                const int p   = atomicAdd(&sm.a.cur[b], 1);
                sm.a.sorted[p] = make_int2((low << 20) | ss[j], __float_as_int(ww[j]));
                sm.a.binof[p]  = (unsigned short)b;
            }
        }
        __syncthreads();

        #pragma unroll
        for (int k = 0; k < EPB / 512; ++k) {
            const int i = k * 512 + t;
            if (i >= nblk) break;
            const int b    = sm.a.binof[i];
            const int idx  = i - sm.a.start[b];
            const int gpos = sm.a.gbase[b] + idx;
            const int2 e   = sm.a.sorted[i];
            if (gpos < BIN_CAP) {
                payload[(size_t)b * BIN_CAP + gpos] = e;
            } else {
                const int op = atomicAdd(&misc[32], 1);
                if (op < OVF_CAP)
                    ovf[op] = make_int4((b << BIN_SHIFT) + (e.x >> 20),
                                        e.x & 0xFFFFF, e.y, 0);
            }
        }
        __syncthreads();
    }

    // ---- phase A2: x -> bf16 conversion (work-stealing tiles) ----
    for (;;) {
        if (t == 0) sc = atomicAdd(&misc[16], 1);
        __syncthreads();
        const int tile = sc;
        __syncthreads();
        if (tile >= nconv) break;
        const int i0 = tile * CONV_TILE;
        #pragma unroll
        for (int k = 0; k < CONV_TILE / 512; ++k) {
            const int i = i0 + k * 512 + t;
            if (i < n4) {
                const float4 v = reinterpret_cast<const float4*>(x)[i];
                ushort4 o;
                o.x = f32_to_bf16_rn(v.x);
                o.y = f32_to_bf16_rn(v.y);
                o.z = f32_to_bf16_rn(v.z);
                o.w = f32_to_bf16_rn(v.w);
                reinterpret_cast<ushort4*>(xb)[i] = o;
            }
        }
    }

    cg::this_grid().sync();

    // ---- phase B: per-bin fine sort + 8-nodes-per-wave gather ----
    const int sub = lane >> 3;           // node slot within the wave batch
    const int fq  = lane & 7;            // feature octet
    const int fg  = fq * 8;
    const int novf = misc[32];

    #define XROW(SRC) (*reinterpret_cast<const uint4*>(xb + (size_t)(SRC) * D_FEAT + fg))

    for (int b = bid; b < nbins; b += gsz) {
        const int m = min(gcnt[b], BIN_CAP);
        const int2* pl = payload + (size_t)b * BIN_CAP;

        if (t < NODES_PER_BIN) sm.b.ncnt[t] = 0;
        __syncthreads();

        for (int i = t; i < m; i += 512) {
            const int2 e = pl[i];
            sm.b.sraw[i] = e;
            atomicAdd(&sm.b.ncnt[e.x >> 20], 1);
        }
        __syncthreads();

        if (t < 64) {
            const int c0 = sm.b.ncnt[t], c1 = sm.b.ncnt[64 + t];
            const int s0_ = wave_incl_scan(c0, t);
            const int s1_ = wave_incl_scan(c1, t);
            const int tot0 = __shfl(s0_, 63);
            const int e0 = s0_ - c0;
            const int e1 = tot0 + s1_ - c1;
            sm.b.nstart[t]      = e0;  sm.b.ncur[t]      = e0;
            sm.b.nstart[64 + t] = e1;  sm.b.ncur[64 + t] = e1;
            if (t == 63) sm.b.nstart[128] = tot0 + s1_;
        }
        __syncthreads();

        for (int i = t; i < m; i += 512) {
            const int2 e = sm.b.sraw[i];
            const int p  = atomicAdd(&sm.b.ncur[e.x >> 20], 1);
            sm.b.sedge[p] = e;
        }
        __syncthreads();

        #pragma unroll
        for (int nb = 0; nb < 16; nb += 8) {
            const int n    = wid * 16 + nb + sub;
            const int node = (b << BIN_SHIFT) + n;
            const int s0 = sm.b.nstart[n];
            const int s1 = sm.b.nstart[n + 1];

            float a0 = 0.f, a1 = 0.f, a2 = 0.f, a3 = 0.f;
            float a4 = 0.f, a5 = 0.f, a6 = 0.f, a7 = 0.f;

            int e = s0;
            for (; e + 4 <= s1; e += 4) {
                const int2 pA = sm.b.sedge[e];
                const int2 pB = sm.b.sedge[e + 1];
                const int2 pC = sm.b.sedge[e + 2];
                const int2 pD = sm.b.sedge[e + 3];
                const uint4 xA = XROW(pA.x & 0xFFFFF);
                const uint4 xB = XROW(pB.x & 0xFFFFF);
                const uint4 xC = XROW(pC.x & 0xFFFFF);
                const uint4 xD = XROW(pD.x & 0xFFFFF);
                const float wA = __int_as_float(pA.y);
                const float wB = __int_as_float(pB.y);
                const float wC = __int_as_float(pC.y);
                const float wD = __int_as_float(pD.y);
                ACC8(xA, wA);
                ACC8(xB, wB);
                ACC8(xC, wC);
                ACC8(xD, wD);
            }
            if (e + 2 <= s1) {
                const int2 pA = sm.b.sedge[e];
                const int2 pB = sm.b.sedge[e + 1];
                const uint4 xA = XROW(pA.x & 0xFFFFF);
                const uint4 xB = XROW(pB.x & 0xFFFFF);
                const float wA = __int_as_float(pA.y);
                const float wB = __int_as_float(pB.y);
                ACC8(xA, wA);
                ACC8(xB, wB);
                e += 2;
            }
            if (e < s1) {
                const int2 p = sm.b.sedge[e];
                const uint4 xv = XROW(p.x & 0xFFFFF);
                const float ww = __int_as_float(p.y);
                ACC8(xv, ww);
            }

            if (node < n_nodes) {
                if (novf > 0) {  // rare overflow path (fp32 x)
                    const int lim = min(novf, OVF_CAP);
                    for (int j = 0; j < lim; ++j) {
                        const int4 o = ovf[j];
                        if (o.x == node) {
                            const float* xr = x + (size_t)o.y * D_FEAT + fg;
                            const float ww = __int_as_float(o.z);
                            a0 = fmaf(xr[0], ww, a0); a1 = fmaf(xr[1], ww, a1);
                            a2 = fmaf(xr[2], ww, a2); a3 = fmaf(xr[3], ww, a3);
                            a4 = fmaf(xr[4], ww, a4); a5 = fmaf(xr[5], ww, a5);
                            a6 = fmaf(xr[6], ww, a6); a7 = fmaf(xr[7], ww, a7);
                        }
                    }
                }
                float* orow = out + (size_t)node * D_FEAT + fg;
                *reinterpret_cast<float4*>(orow)     = make_float4(a0, a1, a2, a3);
                *reinterpret_cast<float4*>(orow + 4) = make_float4(a4, a5, a6, a7);
            }
        }
        __syncthreads();
    }
    #undef XROW
}

// ---------------- fallback: atomic scatter (round-1, known correct) ----------------
__global__ __launch_bounds__(256) void mp_scatter_atomic(
    const float* __restrict__ x, const int* __restrict__ src,
    const int* __restrict__ dst, const float* __restrict__ w,
    float* __restrict__ out, int n_edges)
{
    const int gtid = blockIdx.x * blockDim.x + threadIdx.x;
    const int edge = gtid >> 6;
    const int lane = threadIdx.x & 63;
    if (edge >= n_edges) return;
    const int s = src[edge];
    const int d = dst[edge];
    const float ww = w[edge];
    atomicAdd(&out[(size_t)d * D_FEAT + lane], x[(size_t)s * D_FEAT + lane] * ww);
}

extern "C" void kernel_launch(void* const* d_in, const int* in_sizes, int n_in,
                              void* d_out, int out_size, void* d_ws, size_t ws_size,
                              hipStream_t stream)
{
    const float* x          = (const float*)d_in[0];
    const int*   edge_index = (const int*)d_in[1];   // [2, E]
    const float* w          = (const float*)d_in[2]; // [E, 1]
    float*       out        = (float*)d_out;

    const int n_edges = in_sizes[1] / 2;
    const int n_nodes = in_sizes[0] / D_FEAT;
    const int* src = edge_index;
    const int* dst = edge_index + n_edges;

    const int nbins   = (n_nodes + NODES_PER_BIN - 1) >> BIN_SHIFT;
    const int nchunks = (n_edges + EPB - 1) / EPB;
    const int n4      = n_nodes * (D_FEAT / 4);
    const int nconv   = (n4 + CONV_TILE - 1) / CONV_TILE;

    // ws layout: gcnt[NBINS_MAX] | misc[64] | ovf[OVF_CAP] int4
    //          | payload[nbins*BIN_CAP] int2 | xb[n_nodes*64] bf16
    int*    gcnt    = (int*)d_ws;
    int*    misc    = gcnt + NBINS_MAX;
    int4*   ovf     = (int4*)(gcnt + NBINS_MAX + 64);
    int2*   payload = (int2*)(ovf + OVF_CAP);
    ushort* xb      = (ushort*)(payload + (size_t)nbins * BIN_CAP);
    const size_t need = (size_t)(NBINS_MAX + 64) * 4 + (size_t)OVF_CAP * 16
                      + (size_t)nbins * BIN_CAP * 8
                      + (size_t)n_nodes * D_FEAT * 2;

    // cooperative grid sizing (host-only queries; graph-capture safe; cached)
    static int s_grid = -1;
    if (s_grid < 0) {
        hipDeviceProp_t prop;
        if (hipGetDeviceProperties(&prop, 0) == hipSuccess) {
            int bpc = 0;
            if (hipOccupancyMaxActiveBlocksPerMultiprocessor(&bpc, mp_fused, 512, 0)
                    == hipSuccess && bpc > 0)
                s_grid = bpc * prop.multiProcessorCount;
            else
                s_grid = 0;
        } else {
            s_grid = 0;
        }
    }

    const bool ok = (ws_size >= need) && (nbins <= NBINS_MAX) && ((n_edges & 3) == 0)
                 && ((n_nodes * D_FEAT) % 4 == 0) && (n_nodes <= 131072)
                 && (s_grid > 0);

    if (ok) {
        int grid = s_grid;
        if (grid > 2048) grid = 2048;
        void* args[] = {
            (void*)&src, (void*)&dst, (void*)&w, (void*)&x,
            (void*)&xb, (void*)&n4,
            (void*)&gcnt, (void*)&payload, (void*)&misc, (void*)&ovf,
            (void*)&out,
            (void*)&n_edges, (void*)&n_nodes, (void*)&nbins,
            (void*)&nchunks, (void*)&nconv
        };
        hipLaunchCooperativeKernel((void*)mp_fused, dim3(grid), dim3(512),
                                   args, 0, stream);
        return;
    }

    // fallback: atomic scatter
    hipMemsetAsync(d_out, 0, (size_t)out_size * sizeof(float), stream);
    const int grid = (int)(((size_t)n_edges * 64 + 255) / 256);
    mp_scatter_atomic<<<grid, 256, 0, stream>>>(x, src, dst, w, out, n_edges);
}

// Round 9
// 138.715 us; speedup vs baseline: 1.4391x; 1.4391x over previous
//
#include <hip/hip_runtime.h>

// MessagePassing: out[dst[e], :] += x[src[e], :] * w[e]
// x: [N, 64] f32, edge_index: [2, E] int32 (row0=src, row1=dst), w: [E,1] f32
// out: [N, 64] f32
//
// Round-18: revert r17's cooperative fusion (190 us: grid-sync + work-steal
// serialization). Back to the r10 two-kernel structure, minus the bf16
// intermediate: r10/r14/r15 nulls showed the gather is issue-bound, not
// bytes-bound, so gathering f32 x directly costs ~nothing in K2 (2 loads
// instead of 1, FEWER VALU ops - no unpack) while deleting K1's whole
// conversion stream (25.6+12.8 MB + VALU) and the xb buffer. K1 is now a
// pure partition (~24 MB traffic). Output is exact f32.

constexpr int D_FEAT        = 64;
constexpr int BIN_SHIFT     = 7;                  // 128 nodes / bin
constexpr int NODES_PER_BIN = 1 << BIN_SHIFT;
constexpr int NBINS_MAX     = 1024;               // supports n_nodes <= 131072
constexpr int BIN_CAP       = 2048;               // mean 1536 at E/N=12 -> +13 sigma
constexpr int EPB           = 4096;               // edges per partition block
constexpr int OVF_CAP       = 32768;

__device__ __forceinline__ int wave_incl_scan(int v, int lane) {
    #pragma unroll
    for (int d = 1; d < 64; d <<= 1) {
        int t = __shfl_up(v, d);
        if (lane >= d) v += t;
    }
    return v;
}

// ---------------- K1: partition edges into coarse bins ----------------
__global__ __launch_bounds__(1024) void mp_partition(
    const int* __restrict__ src, const int* __restrict__ dst,
    const float* __restrict__ w,
    int*  __restrict__ gcnt,       // [nbins] global per-bin cursors (pre-zeroed)
    int2* __restrict__ payload,    // [nbins * BIN_CAP]
    int*  __restrict__ ovf_cnt, int4* __restrict__ ovf,
    int n_edges, int nbins)
{
    __shared__ int cnt[NBINS_MAX];
    __shared__ int start[NBINS_MAX];
    __shared__ int cur[NBINS_MAX];
    __shared__ int gbase[NBINS_MAX];
    __shared__ unsigned short binof[EPB];
    __shared__ int2 sorted[EPB];
    __shared__ int wsum[16];

    const int t    = threadIdx.x;
    const int lane = t & 63;
    const int wid  = t >> 6;
    const int base = blockIdx.x * EPB;
    const int nblk = min(EPB, n_edges - base);

    if (t < NBINS_MAX) cnt[t] = 0;

    const int i4 = (base >> 2) + t;
    const bool have = (i4 * 4 < n_edges);
    int4 d4 = make_int4(0, 0, 0, 0);
    if (have) d4 = reinterpret_cast<const int4*>(dst)[i4];
    __syncthreads();

    if (have) {
        atomicAdd(&cnt[d4.x >> BIN_SHIFT], 1);
        atomicAdd(&cnt[d4.y >> BIN_SHIFT], 1);
        atomicAdd(&cnt[d4.z >> BIN_SHIFT], 1);
        atomicAdd(&cnt[d4.w >> BIN_SHIFT], 1);
    }
    __syncthreads();

    const int c = (t < nbins) ? cnt[t] : 0;
    const int incl = wave_incl_scan(c, lane);
    if (lane == 63) wsum[wid] = incl;
    __syncthreads();
    int woff = 0;
    #pragma unroll
    for (int k = 0; k < 16; ++k) woff += (k < wid) ? wsum[k] : 0;
    const int excl = woff + incl - c;
    if (t < nbins) {
        start[t] = excl;
        cur[t]   = excl;
        if (c > 0) gbase[t] = atomicAdd(&gcnt[t], c);
    }
    __syncthreads();

    if (have) {
        const int4   s4 = reinterpret_cast<const int4*>(src)[i4];
        const float4 w4 = reinterpret_cast<const float4*>(w)[i4];
        const int   dd[4] = {d4.x, d4.y, d4.z, d4.w};
        const int   ss[4] = {s4.x, s4.y, s4.z, s4.w};
        const float ww[4] = {w4.x, w4.y, w4.z, w4.w};
        #pragma unroll
        for (int j = 0; j < 4; ++j) {
            const int b   = dd[j] >> BIN_SHIFT;
            const int low = dd[j] & (NODES_PER_BIN - 1);
            const int p   = atomicAdd(&cur[b], 1);
            sorted[p] = make_int2((low << 20) | ss[j], __float_as_int(ww[j]));
            binof[p]  = (unsigned short)b;
        }
    }
    __syncthreads();

    #pragma unroll
    for (int k = 0; k < EPB / 1024; ++k) {
        const int i = k * 1024 + t;
        if (i >= nblk) break;
        const int b    = binof[i];
        const int idx  = i - start[b];
        const int gpos = gbase[b] + idx;
        const int2 e   = sorted[i];
        if (gpos < BIN_CAP) {
            payload[(size_t)b * BIN_CAP + gpos] = e;
        } else {
            const int op = atomicAdd(ovf_cnt, 1);
            if (op < OVF_CAP)
                ovf[op] = make_int4((b << BIN_SHIFT) + (e.x >> 20),
                                    e.x & 0xFFFFF, e.y, 0);
        }
    }
}

// ---------------- K2: per-bin fine sort (LDS) + 8-nodes-per-wave f32 gather ----------------

#define ACC8F(X0, X1, WW) do {                     \
    a0 = fmaf((X0).x, (WW), a0);                   \
    a1 = fmaf((X0).y, (WW), a1);                   \
    a2 = fmaf((X0).z, (WW), a2);                   \
    a3 = fmaf((X0).w, (WW), a3);                   \
    a4 = fmaf((X1).x, (WW), a4);                   \
    a5 = fmaf((X1).y, (WW), a5);                   \
    a6 = fmaf((X1).z, (WW), a6);                   \
    a7 = fmaf((X1).w, (WW), a7);                   \
} while (0)

__global__ __launch_bounds__(512) void mp_bin_gather(
    const float* __restrict__ x,       // f32 x rows (256 B)
    const int*  __restrict__ gcnt,
    const int2* __restrict__ payload,
    const int*  __restrict__ ovf_cnt, const int4* __restrict__ ovf,
    float* __restrict__ out, int n_nodes)
{
    __shared__ int2 sraw[BIN_CAP];                  // 16 KB (global staged once)
    __shared__ int2 sedge[BIN_CAP];                 // 16 KB (node-sorted)
    __shared__ int ncnt[NODES_PER_BIN];
    __shared__ int nstart[NODES_PER_BIN + 1];
    __shared__ int ncur[NODES_PER_BIN];

    const int b    = blockIdx.x;
    const int t    = threadIdx.x;
    const int wid  = t >> 6;
    const int lane = t & 63;
    const int sub  = lane >> 3;          // node slot within the wave batch
    const int fq   = lane & 7;           // feature octet
    const int fg   = fq * 8;

    const int m = min(gcnt[b], BIN_CAP);
    const int2* pl = payload + (size_t)b * BIN_CAP;

    if (t < NODES_PER_BIN) ncnt[t] = 0;
    __syncthreads();

    // stage payload into LDS once + histogram by node
    for (int i = t; i < m; i += 512) {
        const int2 e = pl[i];
        sraw[i] = e;
        atomicAdd(&ncnt[e.x >> 20], 1);
    }
    __syncthreads();

    // exclusive prefix over 128 node counters (wave 0); write ncur directly
    if (t < 64) {
        const int c0 = ncnt[t], c1 = ncnt[64 + t];
        const int s0_ = wave_incl_scan(c0, t);
        const int s1_ = wave_incl_scan(c1, t);
        const int tot0 = __shfl(s0_, 63);
        const int e0 = s0_ - c0;
        const int e1 = tot0 + s1_ - c1;
        nstart[t]      = e0;  ncur[t]      = e0;
        nstart[64 + t] = e1;  ncur[64 + t] = e1;
        if (t == 63) nstart[128] = tot0 + s1_;
    }
    __syncthreads();

    // LDS -> LDS node-sorted scatter
    for (int i = t; i < m; i += 512) {
        const int2 e = sraw[i];
        const int p  = atomicAdd(&ncur[e.x >> 20], 1);
        sedge[p] = e;
    }
    __syncthreads();

    const int novf = *ovf_cnt;  // usually 0

    #define XR0(SRC) (*reinterpret_cast<const float4*>(x + (size_t)(SRC) * D_FEAT + fg))
    #define XR1(SRC) (*reinterpret_cast<const float4*>(x + (size_t)(SRC) * D_FEAT + fg + 4))

    // gather: 8 nodes per wave in parallel (8-lane group per node).
    // Wave wid owns nodes [wid*16, wid*16+16) as 2 batches of 8.
    #pragma unroll
    for (int nb = 0; nb < 16; nb += 8) {
        const int n    = wid * 16 + nb + sub;
        const int node = (b << BIN_SHIFT) + n;
        const int s0 = nstart[n];
        const int s1 = nstart[n + 1];        // nodes >= n_nodes have s1==s0

        float a0 = 0.f, a1 = 0.f, a2 = 0.f, a3 = 0.f;
        float a4 = 0.f, a5 = 0.f, a6 = 0.f, a7 = 0.f;

        int e = s0;
        for (; e + 4 <= s1; e += 4) {        // 4 rows/group in flight (8 loads)
            const int2 pA = sedge[e];
            const int2 pB = sedge[e + 1];
            const int2 pC = sedge[e + 2];
            const int2 pD = sedge[e + 3];
            const int sA = pA.x & 0xFFFFF, sB = pB.x & 0xFFFFF;
            const int sC = pC.x & 0xFFFFF, sD = pD.x & 0xFFFFF;
            const float4 xA0 = XR0(sA), xA1 = XR1(sA);
            const float4 xB0 = XR0(sB), xB1 = XR1(sB);
            const float4 xC0 = XR0(sC), xC1 = XR1(sC);
            const float4 xD0 = XR0(sD), xD1 = XR1(sD);
            const float wA = __int_as_float(pA.y);
            const float wB = __int_as_float(pB.y);
            const float wC = __int_as_float(pC.y);
            const float wD = __int_as_float(pD.y);
            ACC8F(xA0, xA1, wA);
            ACC8F(xB0, xB1, wB);
            ACC8F(xC0, xC1, wC);
            ACC8F(xD0, xD1, wD);
        }
        if (e + 2 <= s1) {
            const int2 pA = sedge[e];
            const int2 pB = sedge[e + 1];
            const int sA = pA.x & 0xFFFFF, sB = pB.x & 0xFFFFF;
            const float4 xA0 = XR0(sA), xA1 = XR1(sA);
            const float4 xB0 = XR0(sB), xB1 = XR1(sB);
            const float wA = __int_as_float(pA.y);
            const float wB = __int_as_float(pB.y);
            ACC8F(xA0, xA1, wA);
            ACC8F(xB0, xB1, wB);
            e += 2;
        }
        if (e < s1) {
            const int2 p = sedge[e];
            const int sA = p.x & 0xFFFFF;
            const float4 x0 = XR0(sA), x1 = XR1(sA);
            const float ww = __int_as_float(p.y);
            ACC8F(x0, x1, ww);
        }

        if (node < n_nodes) {
            if (novf > 0) {  // rare overflow path
                const int lim = min(novf, OVF_CAP);
                for (int j = 0; j < lim; ++j) {
                    const int4 o = ovf[j];
                    if (o.x == node) {
                        const float* xr = x + (size_t)o.y * D_FEAT + fg;
                        const float ww = __int_as_float(o.z);
                        a0 = fmaf(xr[0], ww, a0); a1 = fmaf(xr[1], ww, a1);
                        a2 = fmaf(xr[2], ww, a2); a3 = fmaf(xr[3], ww, a3);
                        a4 = fmaf(xr[4], ww, a4); a5 = fmaf(xr[5], ww, a5);
                        a6 = fmaf(xr[6], ww, a6); a7 = fmaf(xr[7], ww, a7);
                    }
                }
            }
            float* orow = out + (size_t)node * D_FEAT + fg;
            *reinterpret_cast<float4*>(orow)     = make_float4(a0, a1, a2, a3);
            *reinterpret_cast<float4*>(orow + 4) = make_float4(a4, a5, a6, a7);
        }
    }
    #undef XR0
    #undef XR1
}

// ---------------- fallback: atomic scatter (round-1, known correct) ----------------
__global__ __launch_bounds__(256) void mp_scatter_atomic(
    const float* __restrict__ x, const int* __restrict__ src,
    const int* __restrict__ dst, const float* __restrict__ w,
    float* __restrict__ out, int n_edges)
{
    const int gtid = blockIdx.x * blockDim.x + threadIdx.x;
    const int edge = gtid >> 6;
    const int lane = threadIdx.x & 63;
    if (edge >= n_edges) return;
    const int s = src[edge];
    const int d = dst[edge];
    const float ww = w[edge];
    atomicAdd(&out[(size_t)d * D_FEAT + lane], x[(size_t)s * D_FEAT + lane] * ww);
}

extern "C" void kernel_launch(void* const* d_in, const int* in_sizes, int n_in,
                              void* d_out, int out_size, void* d_ws, size_t ws_size,
                              hipStream_t stream)
{
    const float* x          = (const float*)d_in[0];
    const int*   edge_index = (const int*)d_in[1];   // [2, E]
    const float* w          = (const float*)d_in[2]; // [E, 1]
    float*       out        = (float*)d_out;

    const int n_edges = in_sizes[1] / 2;
    const int n_nodes = in_sizes[0] / D_FEAT;
    const int* src = edge_index;
    const int* dst = edge_index + n_edges;

    const int nbins = (n_nodes + NODES_PER_BIN - 1) >> BIN_SHIFT;

    // ws layout: gcnt[NBINS_MAX] | ovf_cnt(+pad 64 ints) | ovf[OVF_CAP] int4
    //          | payload[nbins*BIN_CAP] int2
    int*    gcnt    = (int*)d_ws;
    int*    ovf_cnt = gcnt + NBINS_MAX;
    int4*   ovf     = (int4*)(gcnt + NBINS_MAX + 64);
    int2*   payload = (int2*)(ovf + OVF_CAP);
    const size_t need = (size_t)(NBINS_MAX + 64) * 4 + (size_t)OVF_CAP * 16
                      + (size_t)nbins * BIN_CAP * 8;

    const bool ok = (ws_size >= need) && (nbins <= NBINS_MAX) && ((n_edges & 3) == 0)
                 && (n_nodes <= 131072);

    if (ok) {
        hipMemsetAsync(gcnt, 0, (size_t)(NBINS_MAX + 64) * 4, stream);
        const int g1 = (n_edges + EPB - 1) / EPB;
        mp_partition<<<g1, 1024, 0, stream>>>(src, dst, w,
                                              gcnt, payload, ovf_cnt, ovf,
                                              n_edges, nbins);
        mp_bin_gather<<<nbins, 512, 0, stream>>>(x, gcnt, payload,
                                                 ovf_cnt, ovf, out, n_nodes);
        return;
    }

    // fallback: atomic scatter
    hipMemsetAsync(d_out, 0, (size_t)out_size * sizeof(float), stream);
    const int grid = (int)(((size_t)n_edges * 64 + 255) / 256);
    mp_scatter_atomic<<<grid, 256, 0, stream>>>(x, src, dst, w, out, n_edges);
}